// Round 3
// baseline (272.047 us; speedup 1.0000x reference)
//
#include <hip/hip_runtime.h>
#include <math.h>

#define BATCH 256
#define QL 50
#define EMB 50
#define DL 2000
#define NB 11
#define SEG 4        // d-dimension split per batch -> 1024 blocks
#define RPS 500      // rows per segment (DL/SEG)
#define TPB 256
#define QPAD 52      // q row padded to 52 floats -> 208B, 16B-aligned ds_read_b128

// ---------------- main kernel: cosine sim + histogram ----------------
// Structure: e-outer / q-inner with 50 accumulators per d-row. Accumulators
// are RMW every step -> compiler MUST keep them in VGPRs (no remat possible,
// unlike R1 where loaded d-rows were re-read 50x from cache, 130us).
__global__ __launch_bounds__(TPB, 2)
void sim_hist_kernel(const float* __restrict__ qe,   // [B,QL,EMB]
                     const float* __restrict__ de,   // [B,DL,EMB]
                     const int*   __restrict__ qid,  // [B,QL]
                     const int*   __restrict__ did,  // [B,DL]
                     unsigned*    __restrict__ g_hist) // [B,QL,NB]
{
    const int bid = blockIdx.x;
    const int b   = bid >> 2;
    const int seg = bid & 3;
    const int t   = threadIdx.x;

    __shared__ __align__(16) float s_q[QL * QPAD];   // raw q rows, zero-padded
    __shared__ float    s_qrn[QL];
    __shared__ int      s_qv[QL];
    __shared__ unsigned s_hist[QL * NB];

    const float* qbase = qe + (size_t)b * QL * EMB;

    // cooperative staging of raw q rows (zero pad cols 50,51)
    for (int i = t; i < QL * QPAD; i += TPB) {
        const int q = i / QPAD;
        const int e = i - q * QPAD;
        s_q[i] = (e < EMB) ? qbase[q * EMB + e] : 0.f;
    }
    for (int i = t; i < QL * NB; i += TPB) s_hist[i] = 0u;
    if (t < QL) {
        const float* qr = qbase + t * EMB;
        float ss = 0.f;
        #pragma unroll
        for (int e = 0; e < EMB; ++e) ss = fmaf(qr[e], qr[e], ss);
        s_qrn[t] = 1.0f / (sqrtf(ss) + 1e-8f);
        s_qv[t]  = (qid[(size_t)b * QL + t] > 0) ? 1 : 0;
    }
    __syncthreads();

    // this thread's two d rows
    const int  l0 = t, l1 = t + TPB;
    const bool ok0 = (l0 < RPS), ok1 = (l1 < RPS);
    const int  row0 = seg * RPS + (ok0 ? l0 : 0);
    const int  row1 = seg * RPS + (ok1 ? l1 : 0);
    const float* dr0 = de + ((size_t)b * DL + row0) * EMB;
    const float* dr1 = de + ((size_t)b * DL + row1) * EMB;
    const int dval0 = (ok0 && did[(size_t)b * DL + row0] > 0) ? 1 : 0;
    const int dval1 = (ok1 && did[(size_t)b * DL + row1] > 0) ? 1 : 0;

    float acc0[QL], acc1[QL];
    #pragma unroll
    for (int q = 0; q < QL; ++q) { acc0[q] = 0.f; acc1[q] = 0.f; }
    float ss0 = 0.f, ss1 = 0.f;

    // ---- main loop: 12 full float4 steps (e = 0..47) ----
    #pragma unroll 1
    for (int e4 = 0; e4 < 12; ++e4) {
        const int e = e4 * 4;
        // d rows are 200B (not 16B aligned) -> two float2 loads per row
        const float2 a0 = *(const float2*)(dr0 + e);
        const float2 b0 = *(const float2*)(dr0 + e + 2);
        const float2 a1 = *(const float2*)(dr1 + e);
        const float2 b1 = *(const float2*)(dr1 + e + 2);
        // norms accumulated in e-ascending fmaf order (bit-match R1)
        ss0 = fmaf(a0.x, a0.x, ss0); ss0 = fmaf(a0.y, a0.y, ss0);
        ss0 = fmaf(b0.x, b0.x, ss0); ss0 = fmaf(b0.y, b0.y, ss0);
        ss1 = fmaf(a1.x, a1.x, ss1); ss1 = fmaf(a1.y, a1.y, ss1);
        ss1 = fmaf(b1.x, b1.x, ss1); ss1 = fmaf(b1.y, b1.y, ss1);
        #pragma unroll
        for (int q = 0; q < QL; ++q) {
            const float4 qv = *(const float4*)&s_q[q * QPAD + e];  // uniform addr -> broadcast
            float t0 = acc0[q];
            t0 = fmaf(a0.x, qv.x, t0);
            t0 = fmaf(a0.y, qv.y, t0);
            t0 = fmaf(b0.x, qv.z, t0);
            t0 = fmaf(b0.y, qv.w, t0);
            acc0[q] = t0;
            float t1 = acc1[q];
            t1 = fmaf(a1.x, qv.x, t1);
            t1 = fmaf(a1.y, qv.y, t1);
            t1 = fmaf(b1.x, qv.z, t1);
            t1 = fmaf(b1.y, qv.w, t1);
            acc1[q] = t1;
        }
    }
    // ---- tail: e = 48,49 ----
    {
        const float2 a0 = *(const float2*)(dr0 + 48);
        const float2 a1 = *(const float2*)(dr1 + 48);
        ss0 = fmaf(a0.x, a0.x, ss0); ss0 = fmaf(a0.y, a0.y, ss0);
        ss1 = fmaf(a1.x, a1.x, ss1); ss1 = fmaf(a1.y, a1.y, ss1);
        #pragma unroll
        for (int q = 0; q < QL; ++q) {
            const float4 qv = *(const float4*)&s_q[q * QPAD + 48];
            float t0 = acc0[q];
            t0 = fmaf(a0.x, qv.x, t0);
            t0 = fmaf(a0.y, qv.y, t0);
            acc0[q] = t0;
            float t1 = acc1[q];
            t1 = fmaf(a1.x, qv.x, t1);
            t1 = fmaf(a1.y, qv.y, t1);
            acc1[q] = t1;
        }
    }

    const float drn0 = 1.0f / (sqrtf(ss0) + 1e-8f);
    const float drn1 = 1.0f / (sqrtf(ss1) + 1e-8f);

    // ---- histogram epilogue: direct LDS atomics (short code, unrolled) ----
    #pragma unroll
    for (int q = 0; q < QL; ++q) {
        if (!s_qv[q]) continue;                 // wave-uniform skip
        const float qrn = s_qrn[q];
        {
            const float s  = acc0[q] * qrn * drn0;
            const float tt = ((s + 1.000001f) * 0.5f) * 10.0f;  // match ref order
            int bb = (int)tt;
            bb = bb < 0 ? 0 : (bb > 10 ? 10 : bb);
            if (dval0) atomicAdd(&s_hist[q * NB + bb], 1u);
        }
        {
            const float s  = acc1[q] * qrn * drn1;
            const float tt = ((s + 1.000001f) * 0.5f) * 10.0f;
            int bb = (int)tt;
            bb = bb < 0 ? 0 : (bb > 10 ? 10 : bb);
            if (dval1) atomicAdd(&s_hist[q * NB + bb], 1u);
        }
    }

    __syncthreads();
    for (int i = t; i < QL * NB; i += TPB) {
        const unsigned c = s_hist[i];
        if (c) atomicAdd(&g_hist[(size_t)b * QL * NB + i], c);
    }
}

// ---------------- epilogue 1: ffn dot + gate dot per batch ----------------
__global__ __launch_bounds__(TPB)
void ffn_gate_kernel(const unsigned* __restrict__ g_hist,
                     const float* __restrict__ W1,
                     const float* __restrict__ bias,
                     const float* __restrict__ qe,
                     const float* __restrict__ Wg,
                     float* __restrict__ ffn,
                     float* __restrict__ gate)
{
    const int b = blockIdx.x;
    const int t = threadIdx.x;

    float a1 = 0.f;
    for (int i = t; i < QL * NB; i += TPB)
        a1 = fmaf(logf((float)g_hist[(size_t)b * QL * NB + i] + 1e-5f), W1[i], a1);

    float a2 = 0.f;
    for (int i = t; i < QL * EMB; i += TPB)
        a2 = fmaf(qe[(size_t)b * QL * EMB + i], Wg[i], a2);

    #pragma unroll
    for (int off = 32; off > 0; off >>= 1) {
        a1 += __shfl_down(a1, off, 64);
        a2 += __shfl_down(a2, off, 64);
    }
    __shared__ float r1s[4], r2s[4];
    if ((t & 63) == 0) { r1s[t >> 6] = a1; r2s[t >> 6] = a2; }
    __syncthreads();
    if (t == 0) {
        ffn[b]  = r1s[0] + r1s[1] + r1s[2] + r1s[3] + bias[0];
        gate[b] = r2s[0] + r2s[1] + r2s[2] + r2s[3];
    }
}

// ---------------- epilogue 2: softmax over batch + final score ----------------
__global__ __launch_bounds__(TPB)
void score_kernel(const float* __restrict__ ffn,
                  const float* __restrict__ gate,
                  float* __restrict__ out)
{
    const int t = threadIdx.x;  // one block of 256 == BATCH
    __shared__ float buf[4];
    __shared__ float sM, sZ, sS;

    const float g = gate[t];

    float m = g;
    #pragma unroll
    for (int off = 32; off > 0; off >>= 1) m = fmaxf(m, __shfl_down(m, off, 64));
    if ((t & 63) == 0) buf[t >> 6] = m;
    __syncthreads();
    if (t == 0) sM = fmaxf(fmaxf(buf[0], buf[1]), fmaxf(buf[2], buf[3]));
    __syncthreads();

    const float e = expf(g - sM);
    float z = e;
    #pragma unroll
    for (int off = 32; off > 0; off >>= 1) z += __shfl_down(z, off, 64);
    __syncthreads();
    if ((t & 63) == 0) buf[t >> 6] = z;
    __syncthreads();
    if (t == 0) sZ = buf[0] + buf[1] + buf[2] + buf[3];
    __syncthreads();

    float p = e / sZ;           // out_tgn[t]
    float s = p;
    #pragma unroll
    for (int off = 32; off > 0; off >>= 1) s += __shfl_down(s, off, 64);
    __syncthreads();
    if ((t & 63) == 0) buf[t >> 6] = s;
    __syncthreads();
    if (t == 0) sS = buf[0] + buf[1] + buf[2] + buf[3];   // == sum(softmax) ~ 1
    __syncthreads();

    out[t] = ffn[t] * sS;
}

// ---------------- launcher ----------------
extern "C" void kernel_launch(void* const* d_in, const int* in_sizes, int n_in,
                              void* d_out, int out_size, void* d_ws, size_t ws_size,
                              hipStream_t stream)
{
    const float* qe  = (const float*)d_in[0];
    const float* de  = (const float*)d_in[1];
    const float* W1  = (const float*)d_in[2];
    const float* b1  = (const float*)d_in[3];
    const float* Wg  = (const float*)d_in[4];
    const int*   qid = (const int*)d_in[5];
    const int*   did = (const int*)d_in[6];
    float* out = (float*)d_out;

    unsigned* g_hist = (unsigned*)d_ws;
    const size_t hist_bytes = (size_t)BATCH * QL * NB * sizeof(unsigned); // 563,200 B
    float* ffn  = (float*)((char*)d_ws + hist_bytes);
    float* gate = ffn + BATCH;

    hipMemsetAsync(g_hist, 0, hist_bytes, stream);
    sim_hist_kernel<<<BATCH * SEG, TPB, 0, stream>>>(qe, de, qid, did, g_hist);
    ffn_gate_kernel<<<BATCH, TPB, 0, stream>>>(g_hist, W1, b1, qe, Wg, ffn, gate);
    score_kernel<<<1, TPB, 0, stream>>>(ffn, gate, out);
}